// Round 23
// baseline (724.265 us; speedup 1.0000x reference)
//
#include <hip/hip_runtime.h>
#include <hip/hip_bf16.h>

// WindowAttentionV2: B_NW=2048, N=64, DIM=512, NH=16, DH=32, HID=384, NW=64
// v21 = v19 (best: 683.6us) with qkv q/k passes computing C^T via swapped MFMA
//      operands -> vectorized v4bf epilogue stores (was 64 scalar stores/thread/pass).
//      v pass unchanged (already vectorized). attn_proj = v19 exactly.

typedef __bf16 bf16;
typedef __bf16 v2bf __attribute__((ext_vector_type(2)));
typedef __bf16 v4bf __attribute__((ext_vector_type(4)));
typedef __bf16 v8bf __attribute__((ext_vector_type(8)));
typedef float  v4f  __attribute__((ext_vector_type(4)));

#define AS1 __attribute__((address_space(1)))
#define AS3 __attribute__((address_space(3)))

// A-tile involution (rows stride 1024B): XOR row low-3 bits (o bits 10-12) into bits 4-6.
__device__ __forceinline__ int swzA(int o) { return o ^ (((o >> 10) & 7) << 4); }
// B-tile involution (rows stride 64B): XOR (row>>1)&3 (o bits 7-8) into 16B-slot bits 4-5.
__device__ __forceinline__ int swzB(int o) { return o ^ (((o >> 7) & 3) << 4); }

__device__ __forceinline__ unsigned packbf(float a, float b) {
    v2bf t = { (bf16)a, (bf16)b };
    return __builtin_bit_cast(unsigned, t);
}

// ---------------- K0: weights -> transposed bf16 ----------------
__global__ void convert_w_kernel(const float* __restrict__ wqkv, const float* __restrict__ wout,
                                 bf16* __restrict__ Wt, bf16* __restrict__ WoT) {
    int idx = blockIdx.x * 256 + threadIdx.x;        // 786,432 threads
    Wt[idx] = (bf16)wqkv[(idx & 511) * 1536 + (idx >> 9)];
    if (idx < 262144) WoT[idx] = (bf16)wout[(idx & 511) * 512 + (idx >> 9)];
}

// ---------------- K1a: meta-MLP bias[h][i][j] ----------------
__global__ void bias_kernel(const float* __restrict__ rel_log, const float* __restrict__ w1,
                            const float* __restrict__ b1, const float* __restrict__ w2,
                            const float* __restrict__ b2, float* __restrict__ bias) {
    int p = blockIdx.x * 256 + threadIdx.x;          // (i,j) pair, 4096 total
    float ra = rel_log[p * 2 + 0];
    float rb = rel_log[p * 2 + 1];
    float acc[16];
    #pragma unroll
    for (int t = 0; t < 16; ++t) acc[t] = 0.f;
    for (int kk = 0; kk < 384; ++kk) {
        float hv = fmaxf(ra * w1[kk] + rb * w1[384 + kk] + b1[kk], 0.f);
        #pragma unroll
        for (int t = 0; t < 16; ++t) acc[t] += hv * w2[kk * 16 + t];
    }
    #pragma unroll
    for (int t = 0; t < 16; ++t) bias[t * 4096 + p] = acc[t] + b2[t];
}

// ---------------- K1b: comb swizzled for the SWAPPED (S^T) frag layout ----------------
__global__ void comb_kernel(const float* __restrict__ bias, const float* __restrict__ mask,
                            float* __restrict__ comb) {
    int idx = blockIdx.x * 256 + threadIdx.x;        // 4,194,304 threads (16384 blocks)
    int t = idx & 4095, wh = idx >> 12;
    int w = wh >> 4, h = wh & 15;
    int ji = t >> 8, rem = t & 255;
    int j = ji >> 2, i = ji & 3;
    int q16 = rem >> 2, r = t & 3;
    int lq = q16 >> 4, lm = q16 & 15;
    int p = (i * 16 + lm) * 64 + j * 16 + lq * 4 + r;
    comb[idx] = bias[h * 4096 + p] + mask[w * 4096 + p];
}

// ---------------- K2: qkv GEMM, barrier-free, wave-private async B (v18 loop) ----------------
// q/k passes: acc = mfma(B,A) -> C^T: thread holds q[n=i*16+lm][c=j*16+lq*4+r] -> v4bf stores.
__global__ __launch_bounds__(512, 1) void qkv_fused_kernel(
    const float* __restrict__ x,    // [131072][512] fp32
    const bf16* __restrict__ Wt,    // [1536][512] (L2-resident)
    bf16* __restrict__ q_ws, bf16* __restrict__ k_ws, bf16* __restrict__ v_ws)
{
    __shared__ alignas(16) char Albuf[65536];        // A: 64 x 512 bf16, swizzled
    __shared__ alignas(16) char Blbuf[8][2][4096];   // B: per-wave dbuf, swizzled
    const int mb = blockIdx.x;                       // window index
    const int t = threadIdx.x;
    const int wv = t >> 6, lane = t & 63, lq = lane >> 4, lm = lane & 15;

    {
        const char* xbase = (const char*)x + (size_t)mb * 64 * 2048;
        #pragma unroll
        for (int p = 0; p < 8; ++p) {
            int o = p * 8192 + t * 16;
            const float4* src = (const float4*)(xbase + (size_t)o * 2);
            float4 f0 = src[0], f1 = src[1];
            v8bf a = { (bf16)f0.x, (bf16)f0.y, (bf16)f0.z, (bf16)f0.w,
                       (bf16)f1.x, (bf16)f1.y, (bf16)f1.z, (bf16)f1.w };
            *(v8bf*)(&Albuf[swzA(o)]) = a;
        }
    }

    auto stageB = [&](int buf, int pass, int kt) {
        const char* bBase = (const char*)Wt + (size_t)(pass * 512 + wv * 64) * 1024;
        char* dst = &Blbuf[wv][buf][0];
        #pragma unroll
        for (int p = 0; p < 4; ++p) {
            int o = p * 1024 + lane * 16;
            int s = swzB(o);
            __builtin_amdgcn_global_load_lds(
                (const AS1 void*)(bBase + (size_t)(s >> 6) * 1024 + kt * 64 + (s & 63)),
                (AS3 void*)(dst + o), 16, 0, 0);
        }
    };

    stageB(0, 0, 0);
    __syncthreads();                                 // publish A (the ONLY block barrier)

    int abase[4], boff[4];
    #pragma unroll
    for (int i = 0; i < 4; ++i) {
        int arow = i * 16 + lm;
        abase[i] = (arow * 1024 + lq * 16) ^ ((arow & 7) << 4);
        int brow = i * 16 + lm;
        boff[i] = (brow * 64) + (((lq ^ (brow >> 1)) & 3) * 16);
    }

    const int bw = mb;
    v4f acc[4][4];
    #pragma unroll
    for (int i = 0; i < 4; ++i)
        #pragma unroll
        for (int j = 0; j < 4; ++j) acc[i][j] = v4f{0.f, 0.f, 0.f, 0.f};

    #pragma unroll 1
    for (int ph = 0; ph < 48; ++ph) {
        const int pass = ph >> 4, kt = ph & 15;
        if (ph < 47) {
            const int nph = ph + 1;
            stageB(nph & 1, nph >> 4, nph & 15);
            asm volatile("s_waitcnt vmcnt(4)" ::: "memory");
        } else {
            asm volatile("s_waitcnt vmcnt(0)" ::: "memory");
        }
        __builtin_amdgcn_sched_barrier(0);
        const char* Bb = &Blbuf[wv][ph & 1][0];
        v8bf af[4], bfj[4];
        #pragma unroll
        for (int j = 0; j < 4; ++j) bfj[j] = *(const v8bf*)(Bb + boff[j]);
        #pragma unroll
        for (int i = 0; i < 4; ++i) af[i] = *(const v8bf*)(&Albuf[abase[i] ^ (kt << 6)]);
        if (ph < 32) {   // q/k passes: C^T (thread holds [n][dh-run])
            #pragma unroll
            for (int i = 0; i < 4; ++i)
                #pragma unroll
                for (int j = 0; j < 4; ++j)
                    acc[i][j] = __builtin_amdgcn_mfma_f32_16x16x32_bf16(bfj[j], af[i], acc[i][j], 0, 0, 0);
        } else {         // v pass: normal orientation (transposed store already vectorized)
            #pragma unroll
            for (int i = 0; i < 4; ++i)
                #pragma unroll
                for (int j = 0; j < 4; ++j)
                    acc[i][j] = __builtin_amdgcn_mfma_f32_16x16x32_bf16(af[i], bfj[j], acc[i][j], 0, 0, 0);
        }

        if (kt == 15) {
            if (pass < 2) {
                // C^T: acc[i][j][r] = q[n = i*16+lm][c = j*16+lq*4+r]
                bf16* dst = (pass == 0) ? q_ws : k_ws;
                #pragma unroll
                for (int j = 0; j < 4; ++j) {
                    const int h = wv * 2 + (j >> 1);
                    const int dh0 = (j & 1) * 16 + lq * 4;
                    #pragma unroll
                    for (int i = 0; i < 4; ++i) {
                        const int n = i * 16 + lm;
                        v4bf qv = { (bf16)acc[i][j][0], (bf16)acc[i][j][1],
                                    (bf16)acc[i][j][2], (bf16)acc[i][j][3] };
                        *(v4bf*)(dst + ((size_t)(bw * 16 + h) * 64 + n) * 32 + dh0) = qv;
                    }
                }
            } else {
                #pragma unroll
                for (int j = 0; j < 4; ++j) {
                    const int h = wv * 2 + (j >> 1);
                    const int dh = (j & 1) * 16 + lm;
                    #pragma unroll
                    for (int i = 0; i < 4; ++i) {
                        v4bf pv = { (bf16)acc[i][j][0], (bf16)acc[i][j][1],
                                    (bf16)acc[i][j][2], (bf16)acc[i][j][3] };
                        *(v4bf*)(v_ws + ((size_t)(bw * 16 + h) * 32 + dh) * 64 + i * 16 + lq * 4) = pv;
                    }
                }
            }
            #pragma unroll
            for (int i = 0; i < 4; ++i)
                #pragma unroll
                for (int j = 0; j < 4; ++j) acc[i][j] = v4f{0.f, 0.f, 0.f, 0.f};
        }
    }
}

// ---------------- K3: FUSED attention + out-projection, register-P via shfl (v19) ----------------
__global__ __launch_bounds__(512, 4) void attn_proj_kernel(
    const bf16* __restrict__ q_ws,   // [bw*16+h][64][32] unnormalized
    const bf16* __restrict__ k_ws,
    const bf16* __restrict__ v_ws,   // [bw*16+h][32][64]
    const float* __restrict__ comb,  // [64][16][4096] swizzled for S^T frags
    const float* __restrict__ tau,   // [16]
    const bf16* __restrict__ WoT,    // [512][512]
    const float* __restrict__ b_out, // [512]
    int wofs,
    float* __restrict__ out)         // [rows][512] fp32
{
    __shared__ alignas(16) bf16 AO[64 * 520];        // only LDS: 66.6 KB -> 2 blocks/CU
    const int b = blockIdx.x;
    const int tid = threadIdx.x;
    const int wv = tid >> 6, lane = tid & 63, lq = lane >> 4, lm = lane & 15;
    const v4f z4 = {0.f, 0.f, 0.f, 0.f};
    const int src0 = ((lq & 1) * 2) * 16 + lm;       // shfl sources for PV gather
    const int src1 = src0 + 16;
    const bool hisel = (lq >> 1) != 0;

    #pragma unroll 1
    for (int hh = 0; hh < 2; ++hh) {
        const int h = wv * 2 + hh;
        const size_t qk_base = (size_t)(b * 16 + h) * 64 * 32;
        const float* comb_hw = comb + ((size_t)(((wofs + b) & 63) * 16 + h)) * 4096
                                    + (lq * 16 + lm) * 4;
        const float tau_h = tau[h];

        v8bf qf[4], kf[4];
        #pragma unroll
        for (int i = 0; i < 4; ++i)
            qf[i] = *(const v8bf*)(q_ws + qk_base + (i * 16 + lm) * 32 + lq * 8);
        #pragma unroll
        for (int j = 0; j < 4; ++j)
            kf[j] = *(const v8bf*)(k_ws + qk_base + (j * 16 + lm) * 32 + lq * 8);

        #pragma unroll
        for (int i = 0; i < 4; ++i) {
            float a = 0.f;
            #pragma unroll
            for (int e = 0; e < 8; ++e) { float f = (float)qf[i][e]; a = fmaf(f, f, a); }
            a += __shfl_xor(a, 16); a += __shfl_xor(a, 32);
            float sc = tau_h / fmaxf(sqrtf(a), 1e-12f);
            #pragma unroll
            for (int e = 0; e < 8; ++e) qf[i][e] = (bf16)((float)qf[i][e] * sc);
        }
        #pragma unroll
        for (int j = 0; j < 4; ++j) {
            float a = 0.f;
            #pragma unroll
            for (int e = 0; e < 8; ++e) { float f = (float)kf[j][e]; a = fmaf(f, f, a); }
            a += __shfl_xor(a, 16); a += __shfl_xor(a, 32);
            float sc = 1.0f / fmaxf(sqrtf(a), 1e-12f);
            #pragma unroll
            for (int e = 0; e < 8; ++e) kf[j][e] = (bf16)((float)kf[j][e] * sc);
        }

        v4f st[4][4];
        #pragma unroll
        for (int j = 0; j < 4; ++j)
            #pragma unroll
            for (int i = 0; i < 4; ++i)
                st[j][i] = __builtin_amdgcn_mfma_f32_16x16x32_bf16(kf[j], qf[i], z4, 0, 0, 0);

        #pragma unroll
        for (int j = 0; j < 4; ++j)
            #pragma unroll
            for (int i = 0; i < 4; ++i) {
                float4 cv = *(const float4*)(comb_hw + (j * 4 + i) * 256);
                st[j][i][0] += cv.x; st[j][i][1] += cv.y;
                st[j][i][2] += cv.z; st[j][i][3] += cv.w;
            }

        // softmax over k per q-col i; P packed into registers (bf16 pairs), no LDS
        unsigned p_lo[4][4], p_hi[4][4];             // [j][i]
        #pragma unroll
        for (int i = 0; i < 4; ++i) {
            float mx = st[0][i][0];
            #pragma unroll
            for (int j = 0; j < 4; ++j)
                #pragma unroll
                for (int r = 0; r < 4; ++r) mx = fmaxf(mx, st[j][i][r]);
            mx = fmaxf(mx, __shfl_xor(mx, 16));
            mx = fmaxf(mx, __shfl_xor(mx, 32));
            float sm = 0.f;
            #pragma unroll
            for (int j = 0; j < 4; ++j)
                #pragma unroll
                for (int r = 0; r < 4; ++r) {
                    float e = __expf(st[j][i][r] - mx);
                    st[j][i][r] = e; sm += e;
                }
            sm += __shfl_xor(sm, 16); sm += __shfl_xor(sm, 32);
            float rcp = 1.0f / sm;
            #pragma unroll
            for (int j = 0; j < 4; ++j) {
                p_lo[j][i] = packbf(st[j][i][0] * rcp, st[j][i][1] * rcp);
                p_hi[j][i] = packbf(st[j][i][2] * rcp, st[j][i][3] * rcp);
            }
        }

        // O = P̂ V: PV A-frags gathered via shfl (both jsrc candidates + select)
        const size_t v_base = (size_t)(b * 16 + h) * 32 * 64;
        v4f o[4][2];
        #pragma unroll
        for (int i = 0; i < 4; ++i)
            #pragma unroll
            for (int nt = 0; nt < 2; ++nt) o[i][nt] = z4;
        #pragma unroll
        for (int kk = 0; kk < 2; ++kk) {
            v8bf vf[2];
            #pragma unroll
            for (int nt = 0; nt < 2; ++nt)
                vf[nt] = *(const v8bf*)(v_ws + v_base + (nt * 16 + lm) * 64 + kk * 32 + lq * 8);
            #pragma unroll
            for (int i = 0; i < 4; ++i) {
                unsigned a0 = __shfl((int)p_lo[2 * kk][i], src0);
                unsigned b0 = __shfl((int)p_lo[2 * kk + 1][i], src0);
                unsigned a1 = __shfl((int)p_hi[2 * kk][i], src0);
                unsigned b1 = __shfl((int)p_hi[2 * kk + 1][i], src0);
                unsigned a2 = __shfl((int)p_lo[2 * kk][i], src1);
                unsigned b2 = __shfl((int)p_lo[2 * kk + 1][i], src1);
                unsigned a3 = __shfl((int)p_hi[2 * kk][i], src1);
                unsigned b3 = __shfl((int)p_hi[2 * kk + 1][i], src1);
                union { unsigned u[4]; v8bf v; } c;
                c.u[0] = hisel ? b0 : a0;
                c.u[1] = hisel ? b1 : a1;
                c.u[2] = hisel ? b2 : a2;
                c.u[3] = hisel ? b3 : a3;
                v8bf pf = c.v;
                #pragma unroll
                for (int nt = 0; nt < 2; ++nt)
                    o[i][nt] = __builtin_amdgcn_mfma_f32_16x16x32_bf16(pf, vf[nt], o[i][nt], 0, 0, 0);
            }
        }
        #pragma unroll
        for (int i = 0; i < 4; ++i)
            #pragma unroll
            for (int nt = 0; nt < 2; ++nt)
                #pragma unroll
                for (int r = 0; r < 4; ++r)
                    AO[(i * 16 + lq * 4 + r) * 520 + h * 32 + nt * 16 + lm] = (bf16)o[i][nt][r];
    }

    __syncthreads();

    // ---- out-projection: rows 0..63 x cols wv*64..wv*64+63, K=512 ----
    v4f acc[4][4];
    #pragma unroll
    for (int i = 0; i < 4; ++i)
        #pragma unroll
        for (int j = 0; j < 4; ++j) acc[i][j] = v4f{0.f, 0.f, 0.f, 0.f};

    #pragma unroll 2
    for (int kc = 0; kc < 16; ++kc) {
        v8bf af[4], bfj[4];
        #pragma unroll
        for (int j = 0; j < 4; ++j)
            bfj[j] = *(const v8bf*)(WoT + (size_t)(wv * 64 + j * 16 + lm) * 512 + kc * 32 + lq * 8);
        #pragma unroll
        for (int i = 0; i < 4; ++i)
            af[i] = *(const v8bf*)(AO + (i * 16 + lm) * 520 + kc * 32 + lq * 8);
        #pragma unroll
        for (int i = 0; i < 4; ++i)
            #pragma unroll
            for (int j = 0; j < 4; ++j)
                acc[i][j] = __builtin_amdgcn_mfma_f32_16x16x32_bf16(af[i], bfj[j], acc[i][j], 0, 0, 0);
    }

    #pragma unroll
    for (int j = 0; j < 4; ++j) {
        const int col = wv * 64 + j * 16 + lm;
        const float bo = b_out[col];
        #pragma unroll
        for (int i = 0; i < 4; ++i)
            #pragma unroll
            for (int r = 0; r < 4; ++r)
                out[(size_t)(b * 64 + i * 16 + lq * 4 + r) * 512 + col] = acc[i][j][r] + bo;
    }
}

// ---------------- launch ----------------
extern "C" void kernel_launch(void* const* d_in, const int* in_sizes, int n_in,
                              void* d_out, int out_size, void* d_ws, size_t ws_size,
                              hipStream_t stream) {
    (void)in_sizes; (void)n_in; (void)out_size;
    const float* x       = (const float*)d_in[0];
    const float* mask    = (const float*)d_in[1];
    const float* w_qkv   = (const float*)d_in[2];
    const float* tau     = (const float*)d_in[3];
    const float* mlp_w1  = (const float*)d_in[4];
    const float* mlp_b1  = (const float*)d_in[5];
    const float* mlp_w2  = (const float*)d_in[6];
    const float* mlp_b2  = (const float*)d_in[7];
    const float* w_out   = (const float*)d_in[8];
    const float* b_out   = (const float*)d_in[9];
    const float* rel_log = (const float*)d_in[10];
    float* out = (float*)d_out;

    char* ws = (char*)d_ws;
    bf16*  Wt     = (bf16*)(ws);                     // 1,572,864 B
    bf16*  WoT    = (bf16*)(ws + 1572864);           //   524,288 B
    float* bias   = (float*)(ws + 2097152);          //   262,144 B
    float* comb   = (float*)(ws + 2359296);          //  16,777,216 B
    char*  qkv_base = ws + 19136512;

    size_t avail = (ws_size > 19136512ULL) ? ws_size - 19136512ULL : 0;
    int W = 2048;                                    // 421 MB total; ws = 1 GiB
    while (W > 128 && (size_t)W * 196608ULL > avail) W >>= 1;
    const size_t qkbuf = (size_t)W * 65536;
    bf16* qb = (bf16*)qkv_base;
    bf16* kb = (bf16*)(qkv_base + qkbuf);
    bf16* vb = (bf16*)(qkv_base + 2 * qkbuf);

    convert_w_kernel<<<3072, 256, 0, stream>>>(w_qkv, w_out, Wt, WoT);
    bias_kernel<<<16, 256, 0, stream>>>(rel_log, mlp_w1, mlp_b1, mlp_w2, mlp_b2, bias);
    comb_kernel<<<16384, 256, 0, stream>>>(bias, mask, comb);

    const int nchunk = 2048 / W;
    for (int c = 0; c < nchunk; ++c) {
        const float* xc = x + (size_t)c * W * 64 * 512;
        qkv_fused_kernel<<<W, 512, 0, stream>>>(xc, Wt, qb, kb, vb);
        attn_proj_kernel<<<W, 512, 0, stream>>>(qb, kb, vb, comb, tau, WoT, b_out,
                                                c * W, out + (size_t)c * W * 64 * 512);
    }
}

// Round 24
// 680.552 us; speedup vs baseline: 1.0642x; 1.0642x over previous
//
#include <hip/hip_runtime.h>
#include <hip/hip_bf16.h>

// WindowAttentionV2: B_NW=2048, N=64, DIM=512, NH=16, DH=32, HID=384, NW=64
// v22 = v19 + qkv K-loop SPLIT into two uniform loops:
//      loop1 (ph 0-31, q/k): swapped mfma(B,A) -> C^T -> vectorized v4bf q/k stores.
//      loop2 (ph 32-47, v): normal mfma(A,B) -> vectorized transposed v store (v19).
//      No runtime orientation branch (v21's mistake). attn_proj = v19 exactly.

typedef __bf16 bf16;
typedef __bf16 v2bf __attribute__((ext_vector_type(2)));
typedef __bf16 v4bf __attribute__((ext_vector_type(4)));
typedef __bf16 v8bf __attribute__((ext_vector_type(8)));
typedef float  v4f  __attribute__((ext_vector_type(4)));

#define AS1 __attribute__((address_space(1)))
#define AS3 __attribute__((address_space(3)))

// A-tile involution (rows stride 1024B): XOR row low-3 bits (o bits 10-12) into bits 4-6.
__device__ __forceinline__ int swzA(int o) { return o ^ (((o >> 10) & 7) << 4); }
// B-tile involution (rows stride 64B): XOR (row>>1)&3 (o bits 7-8) into 16B-slot bits 4-5.
__device__ __forceinline__ int swzB(int o) { return o ^ (((o >> 7) & 3) << 4); }

__device__ __forceinline__ unsigned packbf(float a, float b) {
    v2bf t = { (bf16)a, (bf16)b };
    return __builtin_bit_cast(unsigned, t);
}

// ---------------- K0: weights -> transposed bf16 ----------------
__global__ void convert_w_kernel(const float* __restrict__ wqkv, const float* __restrict__ wout,
                                 bf16* __restrict__ Wt, bf16* __restrict__ WoT) {
    int idx = blockIdx.x * 256 + threadIdx.x;        // 786,432 threads
    Wt[idx] = (bf16)wqkv[(idx & 511) * 1536 + (idx >> 9)];
    if (idx < 262144) WoT[idx] = (bf16)wout[(idx & 511) * 512 + (idx >> 9)];
}

// ---------------- K1a: meta-MLP bias[h][i][j] ----------------
__global__ void bias_kernel(const float* __restrict__ rel_log, const float* __restrict__ w1,
                            const float* __restrict__ b1, const float* __restrict__ w2,
                            const float* __restrict__ b2, float* __restrict__ bias) {
    int p = blockIdx.x * 256 + threadIdx.x;          // (i,j) pair, 4096 total
    float ra = rel_log[p * 2 + 0];
    float rb = rel_log[p * 2 + 1];
    float acc[16];
    #pragma unroll
    for (int t = 0; t < 16; ++t) acc[t] = 0.f;
    for (int kk = 0; kk < 384; ++kk) {
        float hv = fmaxf(ra * w1[kk] + rb * w1[384 + kk] + b1[kk], 0.f);
        #pragma unroll
        for (int t = 0; t < 16; ++t) acc[t] += hv * w2[kk * 16 + t];
    }
    #pragma unroll
    for (int t = 0; t < 16; ++t) bias[t * 4096 + p] = acc[t] + b2[t];
}

// ---------------- K1b: comb swizzled for the SWAPPED (S^T) frag layout ----------------
__global__ void comb_kernel(const float* __restrict__ bias, const float* __restrict__ mask,
                            float* __restrict__ comb) {
    int idx = blockIdx.x * 256 + threadIdx.x;        // 4,194,304 threads (16384 blocks)
    int t = idx & 4095, wh = idx >> 12;
    int w = wh >> 4, h = wh & 15;
    int ji = t >> 8, rem = t & 255;
    int j = ji >> 2, i = ji & 3;
    int q16 = rem >> 2, r = t & 3;
    int lq = q16 >> 4, lm = q16 & 15;
    int p = (i * 16 + lm) * 64 + j * 16 + lq * 4 + r;
    comb[idx] = bias[h * 4096 + p] + mask[w * 4096 + p];
}

// ---------------- K2: qkv GEMM, barrier-free, wave-private async B, split loops ----------------
__global__ __launch_bounds__(512, 1) void qkv_fused_kernel(
    const float* __restrict__ x,    // [131072][512] fp32
    const bf16* __restrict__ Wt,    // [1536][512] (L2-resident)
    bf16* __restrict__ q_ws, bf16* __restrict__ k_ws, bf16* __restrict__ v_ws)
{
    __shared__ alignas(16) char Albuf[65536];        // A: 64 x 512 bf16, swizzled
    __shared__ alignas(16) char Blbuf[8][2][4096];   // B: per-wave dbuf, swizzled
    const int mb = blockIdx.x;                       // window index
    const int t = threadIdx.x;
    const int wv = t >> 6, lane = t & 63, lq = lane >> 4, lm = lane & 15;

    {
        const char* xbase = (const char*)x + (size_t)mb * 64 * 2048;
        #pragma unroll
        for (int p = 0; p < 8; ++p) {
            int o = p * 8192 + t * 16;
            const float4* src = (const float4*)(xbase + (size_t)o * 2);
            float4 f0 = src[0], f1 = src[1];
            v8bf a = { (bf16)f0.x, (bf16)f0.y, (bf16)f0.z, (bf16)f0.w,
                       (bf16)f1.x, (bf16)f1.y, (bf16)f1.z, (bf16)f1.w };
            *(v8bf*)(&Albuf[swzA(o)]) = a;
        }
    }

    auto stageB = [&](int buf, int pass, int kt) {
        const char* bBase = (const char*)Wt + (size_t)(pass * 512 + wv * 64) * 1024;
        char* dst = &Blbuf[wv][buf][0];
        #pragma unroll
        for (int p = 0; p < 4; ++p) {
            int o = p * 1024 + lane * 16;
            int s = swzB(o);
            __builtin_amdgcn_global_load_lds(
                (const AS1 void*)(bBase + (size_t)(s >> 6) * 1024 + kt * 64 + (s & 63)),
                (AS3 void*)(dst + o), 16, 0, 0);
        }
    };

    stageB(0, 0, 0);
    __syncthreads();                                 // publish A (the ONLY block barrier)

    int abase[4], boff[4];
    #pragma unroll
    for (int i = 0; i < 4; ++i) {
        int arow = i * 16 + lm;
        abase[i] = (arow * 1024 + lq * 16) ^ ((arow & 7) << 4);
        int brow = i * 16 + lm;
        boff[i] = (brow * 64) + (((lq ^ (brow >> 1)) & 3) * 16);
    }

    const int bw = mb;
    v4f acc[4][4];
    #pragma unroll
    for (int i = 0; i < 4; ++i)
        #pragma unroll
        for (int j = 0; j < 4; ++j) acc[i][j] = v4f{0.f, 0.f, 0.f, 0.f};

    // ---- loop 1: phases 0..31 (q,k passes), SWAPPED orientation -> C^T ----
    #pragma unroll 1
    for (int ph = 0; ph < 32; ++ph) {
        const int pass = ph >> 4, kt = ph & 15;
        {
            const int nph = ph + 1;
            stageB(nph & 1, nph >> 4, nph & 15);
            asm volatile("s_waitcnt vmcnt(4)" ::: "memory");
        }
        __builtin_amdgcn_sched_barrier(0);
        const char* Bb = &Blbuf[wv][ph & 1][0];
        v8bf af[4], bfj[4];
        #pragma unroll
        for (int j = 0; j < 4; ++j) bfj[j] = *(const v8bf*)(Bb + boff[j]);
        #pragma unroll
        for (int i = 0; i < 4; ++i) af[i] = *(const v8bf*)(&Albuf[abase[i] ^ (kt << 6)]);
        #pragma unroll
        for (int i = 0; i < 4; ++i)
            #pragma unroll
            for (int j = 0; j < 4; ++j)
                acc[i][j] = __builtin_amdgcn_mfma_f32_16x16x32_bf16(bfj[j], af[i], acc[i][j], 0, 0, 0);

        if (kt == 15) {
            // C^T: acc[i][j][r] = q[n = i*16+lm][dh-run = (j&1)*16 + lq*4 + r], h = wv*2+(j>>1)
            bf16* dst = (pass == 0) ? q_ws : k_ws;
            #pragma unroll
            for (int j = 0; j < 4; ++j) {
                const int h = wv * 2 + (j >> 1);
                const int dh0 = (j & 1) * 16 + lq * 4;
                #pragma unroll
                for (int i = 0; i < 4; ++i) {
                    const int n = i * 16 + lm;
                    v4bf qv = { (bf16)acc[i][j][0], (bf16)acc[i][j][1],
                                (bf16)acc[i][j][2], (bf16)acc[i][j][3] };
                    *(v4bf*)(dst + ((size_t)(bw * 16 + h) * 64 + n) * 32 + dh0) = qv;
                }
            }
            #pragma unroll
            for (int i = 0; i < 4; ++i)
                #pragma unroll
                for (int j = 0; j < 4; ++j) acc[i][j] = v4f{0.f, 0.f, 0.f, 0.f};
        }
    }

    // ---- loop 2: phases 32..47 (v pass), NORMAL orientation ----
    #pragma unroll 1
    for (int ph = 32; ph < 48; ++ph) {
        const int kt = ph & 15;
        if (ph < 47) {
            const int nph = ph + 1;
            stageB(nph & 1, nph >> 4, nph & 15);
            asm volatile("s_waitcnt vmcnt(4)" ::: "memory");
        } else {
            asm volatile("s_waitcnt vmcnt(0)" ::: "memory");
        }
        __builtin_amdgcn_sched_barrier(0);
        const char* Bb = &Blbuf[wv][ph & 1][0];
        v8bf af[4], bfj[4];
        #pragma unroll
        for (int j = 0; j < 4; ++j) bfj[j] = *(const v8bf*)(Bb + boff[j]);
        #pragma unroll
        for (int i = 0; i < 4; ++i) af[i] = *(const v8bf*)(&Albuf[abase[i] ^ (kt << 6)]);
        #pragma unroll
        for (int i = 0; i < 4; ++i)
            #pragma unroll
            for (int j = 0; j < 4; ++j)
                acc[i][j] = __builtin_amdgcn_mfma_f32_16x16x32_bf16(af[i], bfj[j], acc[i][j], 0, 0, 0);
    }
    // v epilogue (v19 form): acc[i][j][r] = v[n=i*16+lq*4+r][c=j*16+lm]
    #pragma unroll
    for (int j = 0; j < 4; ++j) {
        const int h = wv * 2 + (j >> 1);
        const int dh = (j & 1) * 16 + lm;
        #pragma unroll
        for (int i = 0; i < 4; ++i) {
            v4bf pv = { (bf16)acc[i][j][0], (bf16)acc[i][j][1],
                        (bf16)acc[i][j][2], (bf16)acc[i][j][3] };
            *(v4bf*)(v_ws + ((size_t)(bw * 16 + h) * 32 + dh) * 64 + i * 16 + lq * 4) = pv;
        }
    }
}

// ---------------- K3: FUSED attention + out-projection, register-P via shfl (v19) ----------------
__global__ __launch_bounds__(512, 4) void attn_proj_kernel(
    const bf16* __restrict__ q_ws,   // [bw*16+h][64][32] unnormalized
    const bf16* __restrict__ k_ws,
    const bf16* __restrict__ v_ws,   // [bw*16+h][32][64]
    const float* __restrict__ comb,  // [64][16][4096] swizzled for S^T frags
    const float* __restrict__ tau,   // [16]
    const bf16* __restrict__ WoT,    // [512][512]
    const float* __restrict__ b_out, // [512]
    int wofs,
    float* __restrict__ out)         // [rows][512] fp32
{
    __shared__ alignas(16) bf16 AO[64 * 520];        // only LDS: 66.6 KB -> 2 blocks/CU
    const int b = blockIdx.x;
    const int tid = threadIdx.x;
    const int wv = tid >> 6, lane = tid & 63, lq = lane >> 4, lm = lane & 15;
    const v4f z4 = {0.f, 0.f, 0.f, 0.f};
    const int src0 = ((lq & 1) * 2) * 16 + lm;       // shfl sources for PV gather
    const int src1 = src0 + 16;
    const bool hisel = (lq >> 1) != 0;

    #pragma unroll 1
    for (int hh = 0; hh < 2; ++hh) {
        const int h = wv * 2 + hh;
        const size_t qk_base = (size_t)(b * 16 + h) * 64 * 32;
        const float* comb_hw = comb + ((size_t)(((wofs + b) & 63) * 16 + h)) * 4096
                                    + (lq * 16 + lm) * 4;
        const float tau_h = tau[h];

        v8bf qf[4], kf[4];
        #pragma unroll
        for (int i = 0; i < 4; ++i)
            qf[i] = *(const v8bf*)(q_ws + qk_base + (i * 16 + lm) * 32 + lq * 8);
        #pragma unroll
        for (int j = 0; j < 4; ++j)
            kf[j] = *(const v8bf*)(k_ws + qk_base + (j * 16 + lm) * 32 + lq * 8);

        #pragma unroll
        for (int i = 0; i < 4; ++i) {
            float a = 0.f;
            #pragma unroll
            for (int e = 0; e < 8; ++e) { float f = (float)qf[i][e]; a = fmaf(f, f, a); }
            a += __shfl_xor(a, 16); a += __shfl_xor(a, 32);
            float sc = tau_h / fmaxf(sqrtf(a), 1e-12f);
            #pragma unroll
            for (int e = 0; e < 8; ++e) qf[i][e] = (bf16)((float)qf[i][e] * sc);
        }
        #pragma unroll
        for (int j = 0; j < 4; ++j) {
            float a = 0.f;
            #pragma unroll
            for (int e = 0; e < 8; ++e) { float f = (float)kf[j][e]; a = fmaf(f, f, a); }
            a += __shfl_xor(a, 16); a += __shfl_xor(a, 32);
            float sc = 1.0f / fmaxf(sqrtf(a), 1e-12f);
            #pragma unroll
            for (int e = 0; e < 8; ++e) kf[j][e] = (bf16)((float)kf[j][e] * sc);
        }

        v4f st[4][4];
        #pragma unroll
        for (int j = 0; j < 4; ++j)
            #pragma unroll
            for (int i = 0; i < 4; ++i)
                st[j][i] = __builtin_amdgcn_mfma_f32_16x16x32_bf16(kf[j], qf[i], z4, 0, 0, 0);

        #pragma unroll
        for (int j = 0; j < 4; ++j)
            #pragma unroll
            for (int i = 0; i < 4; ++i) {
                float4 cv = *(const float4*)(comb_hw + (j * 4 + i) * 256);
                st[j][i][0] += cv.x; st[j][i][1] += cv.y;
                st[j][i][2] += cv.z; st[j][i][3] += cv.w;
            }

        unsigned p_lo[4][4], p_hi[4][4];             // [j][i]
        #pragma unroll
        for (int i = 0; i < 4; ++i) {
            float mx = st[0][i][0];
            #pragma unroll
            for (int j = 0; j < 4; ++j)
                #pragma unroll
                for (int r = 0; r < 4; ++r) mx = fmaxf(mx, st[j][i][r]);
            mx = fmaxf(mx, __shfl_xor(mx, 16));
            mx = fmaxf(mx, __shfl_xor(mx, 32));
            float sm = 0.f;
            #pragma unroll
            for (int j = 0; j < 4; ++j)
                #pragma unroll
                for (int r = 0; r < 4; ++r) {
                    float e = __expf(st[j][i][r] - mx);
                    st[j][i][r] = e; sm += e;
                }
            sm += __shfl_xor(sm, 16); sm += __shfl_xor(sm, 32);
            float rcp = 1.0f / sm;
            #pragma unroll
            for (int j = 0; j < 4; ++j) {
                p_lo[j][i] = packbf(st[j][i][0] * rcp, st[j][i][1] * rcp);
                p_hi[j][i] = packbf(st[j][i][2] * rcp, st[j][i][3] * rcp);
            }
        }

        const size_t v_base = (size_t)(b * 16 + h) * 32 * 64;
        v4f o[4][2];
        #pragma unroll
        for (int i = 0; i < 4; ++i)
            #pragma unroll
            for (int nt = 0; nt < 2; ++nt) o[i][nt] = z4;
        #pragma unroll
        for (int kk = 0; kk < 2; ++kk) {
            v8bf vf[2];
            #pragma unroll
            for (int nt = 0; nt < 2; ++nt)
                vf[nt] = *(const v8bf*)(v_ws + v_base + (nt * 16 + lm) * 64 + kk * 32 + lq * 8);
            #pragma unroll
            for (int i = 0; i < 4; ++i) {
                unsigned a0 = __shfl((int)p_lo[2 * kk][i], src0);
                unsigned b0 = __shfl((int)p_lo[2 * kk + 1][i], src0);
                unsigned a1 = __shfl((int)p_hi[2 * kk][i], src0);
                unsigned b1 = __shfl((int)p_hi[2 * kk + 1][i], src0);
                unsigned a2 = __shfl((int)p_lo[2 * kk][i], src1);
                unsigned b2 = __shfl((int)p_lo[2 * kk + 1][i], src1);
                unsigned a3 = __shfl((int)p_hi[2 * kk][i], src1);
                unsigned b3 = __shfl((int)p_hi[2 * kk + 1][i], src1);
                union { unsigned u[4]; v8bf v; } c;
                c.u[0] = hisel ? b0 : a0;
                c.u[1] = hisel ? b1 : a1;
                c.u[2] = hisel ? b2 : a2;
                c.u[3] = hisel ? b3 : a3;
                v8bf pf = c.v;
                #pragma unroll
                for (int nt = 0; nt < 2; ++nt)
                    o[i][nt] = __builtin_amdgcn_mfma_f32_16x16x32_bf16(pf, vf[nt], o[i][nt], 0, 0, 0);
            }
        }
        #pragma unroll
        for (int i = 0; i < 4; ++i)
            #pragma unroll
            for (int nt = 0; nt < 2; ++nt)
                #pragma unroll
                for (int r = 0; r < 4; ++r)
                    AO[(i * 16 + lq * 4 + r) * 520 + h * 32 + nt * 16 + lm] = (bf16)o[i][nt][r];
    }

    __syncthreads();

    // ---- out-projection: rows 0..63 x cols wv*64..wv*64+63, K=512 ----
    v4f acc[4][4];
    #pragma unroll
    for (int i = 0; i < 4; ++i)
        #pragma unroll
        for (int j = 0; j < 4; ++j) acc[i][j] = v4f{0.f, 0.f, 0.f, 0.f};

    #pragma unroll 2
    for (int kc = 0; kc < 16; ++kc) {
        v8bf af[4], bfj[4];
        #pragma unroll
        for (int j = 0; j < 4; ++j)
            bfj[j] = *(const v8bf*)(WoT + (size_t)(wv * 64 + j * 16 + lm) * 512 + kc * 32 + lq * 8);
        #pragma unroll
        for (int i = 0; i < 4; ++i)
            af[i] = *(const v8bf*)(AO + (i * 16 + lm) * 520 + kc * 32 + lq * 8);
        #pragma unroll
        for (int i = 0; i < 4; ++i)
            #pragma unroll
            for (int j = 0; j < 4; ++j)
                acc[i][j] = __builtin_amdgcn_mfma_f32_16x16x32_bf16(af[i], bfj[j], acc[i][j], 0, 0, 0);
    }

    #pragma unroll
    for (int j = 0; j < 4; ++j) {
        const int col = wv * 64 + j * 16 + lm;
        const float bo = b_out[col];
        #pragma unroll
        for (int i = 0; i < 4; ++i)
            #pragma unroll
            for (int r = 0; r < 4; ++r)
                out[(size_t)(b * 64 + i * 16 + lq * 4 + r) * 512 + col] = acc[i][j][r] + bo;
    }
}

// ---------------- launch ----------------
extern "C" void kernel_launch(void* const* d_in, const int* in_sizes, int n_in,
                              void* d_out, int out_size, void* d_ws, size_t ws_size,
                              hipStream_t stream) {
    (void)in_sizes; (void)n_in; (void)out_size;
    const float* x       = (const float*)d_in[0];
    const float* mask    = (const float*)d_in[1];
    const float* w_qkv   = (const float*)d_in[2];
    const float* tau     = (const float*)d_in[3];
    const float* mlp_w1  = (const float*)d_in[4];
    const float* mlp_b1  = (const float*)d_in[5];
    const float* mlp_w2  = (const float*)d_in[6];
    const float* mlp_b2  = (const float*)d_in[7];
    const float* w_out   = (const float*)d_in[8];
    const float* b_out   = (const float*)d_in[9];
    const float* rel_log = (const float*)d_in[10];
    float* out = (float*)d_out;

    char* ws = (char*)d_ws;
    bf16*  Wt     = (bf16*)(ws);                     // 1,572,864 B
    bf16*  WoT    = (bf16*)(ws + 1572864);           //   524,288 B
    float* bias   = (float*)(ws + 2097152);          //   262,144 B
    float* comb   = (float*)(ws + 2359296);          //  16,777,216 B
    char*  qkv_base = ws + 19136512;

    size_t avail = (ws_size > 19136512ULL) ? ws_size - 19136512ULL : 0;
    int W = 2048;                                    // 421 MB total; ws = 1 GiB
    while (W > 128 && (size_t)W * 196608ULL > avail) W >>= 1;
    const size_t qkbuf = (size_t)W * 65536;
    bf16* qb = (bf16*)qkv_base;
    bf16* kb = (bf16*)(qkv_base + qkbuf);
    bf16* vb = (bf16*)(qkv_base + 2 * qkbuf);

    convert_w_kernel<<<3072, 256, 0, stream>>>(w_qkv, w_out, Wt, WoT);
    bias_kernel<<<16, 256, 0, stream>>>(rel_log, mlp_w1, mlp_b1, mlp_w2, mlp_b2, bias);
    comb_kernel<<<16384, 256, 0, stream>>>(bias, mask, comb);

    const int nchunk = 2048 / W;
    for (int c = 0; c < nchunk; ++c) {
        const float* xc = x + (size_t)c * W * 64 * 512;
        qkv_fused_kernel<<<W, 512, 0, stream>>>(xc, Wt, qb, kb, vb);
        attn_proj_kernel<<<W, 512, 0, stream>>>(qb, kb, vb, comb, tau, WoT, b_out,
                                                c * W, out + (size_t)c * W * 64 * 512);
    }
}